// Round 1
// baseline (4679.036 us; speedup 1.0000x reference)
//
#include <hip/hip_runtime.h>
#include <math.h>

// Problem constants
#define NN      65536
#define GG      64
#define NPG     1024
#define KEIG    32
#define NBUN    64
#define BDIM    4
#define CH      256        // IN_CH == GNN_DIM == NB*BD
#define NBP     384
#define NEDGE   524288

__device__ __forceinline__ float gelu_f(float x) {
    return 0.5f * x * (1.0f + erff(x * 0.70710678118654752440f));
}

// ---------------------------------------------------------------------------
// Tiled fp32 GEMM: C[m,n] = act( A@W1 + b1 (+ B@W2 + b2) ) (+ A residual)
// A,B: [NN, 256] row-major.  W: [256, NOUT] row-major.  C: [NN, NOUT].
// Block: 64x64 output tile, 256 threads, 4x4 micro-tile per thread, BK=16.
// ---------------------------------------------------------------------------
template<int NOUT, bool DUAL, bool ACT, bool RES>
__global__ __launch_bounds__(256) void gemm_k(
    const float* __restrict__ A, const float* __restrict__ B,
    const float* __restrict__ W1, const float* __restrict__ bias1,
    const float* __restrict__ W2, const float* __restrict__ bias2,
    float* __restrict__ C)
{
    constexpr int LDT = 68;   // row stride (floats); 272B rows keep float4 16B-aligned
    __shared__ float As[16 * LDT];
    __shared__ float Ws[16 * LDT];
    __shared__ float Bs[DUAL ? 16 * LDT : 1];
    __shared__ float W2s[DUAL ? 16 * LDT : 1];

    const int tid = threadIdx.x;
    const int tx = tid & 15;        // n micro-tile
    const int ty = tid >> 4;        // m micro-tile
    const int m0 = blockIdx.y * 64;
    const int n0 = blockIdx.x * 64;

    // loader coords
    const int lrow  = tid >> 2;          // 0..63  (A row within tile)
    const int lkq   = (tid & 3) * 4;     // 0,4,8,12 (k quad)
    const int lkrow = tid >> 4;          // 0..15  (W k-row)
    const int lnq   = (tid & 15) * 4;    // 0..60  (W n quad)

    const float* Ab  = A + (size_t)(m0 + lrow) * CH + lkq;
    const float* W1b = W1 + (size_t)lkrow * NOUT + n0 + lnq;
    const float* Bb  = DUAL ? (B + (size_t)(m0 + lrow) * CH + lkq) : nullptr;
    const float* W2b = DUAL ? (W2 + (size_t)lkrow * NOUT + n0 + lnq) : nullptr;

    float acc[4][4];
#pragma unroll
    for (int i = 0; i < 4; i++)
#pragma unroll
        for (int j = 0; j < 4; j++) acc[i][j] = 0.f;

    for (int k0 = 0; k0 < CH; k0 += 16) {
        float4 av = *(const float4*)(Ab + k0);
        float4 wv = *(const float4*)(W1b + (size_t)k0 * NOUT);
        float4 bv, w2v;
        if constexpr (DUAL) {
            bv  = *(const float4*)(Bb + k0);
            w2v = *(const float4*)(W2b + (size_t)k0 * NOUT);
        }
        __syncthreads();   // previous iteration's LDS reads done
        As[(lkq + 0) * LDT + lrow] = av.x;
        As[(lkq + 1) * LDT + lrow] = av.y;
        As[(lkq + 2) * LDT + lrow] = av.z;
        As[(lkq + 3) * LDT + lrow] = av.w;
        *(float4*)&Ws[lkrow * LDT + lnq] = wv;
        if constexpr (DUAL) {
            Bs[(lkq + 0) * LDT + lrow] = bv.x;
            Bs[(lkq + 1) * LDT + lrow] = bv.y;
            Bs[(lkq + 2) * LDT + lrow] = bv.z;
            Bs[(lkq + 3) * LDT + lrow] = bv.w;
            *(float4*)&W2s[lkrow * LDT + lnq] = w2v;
        }
        __syncthreads();
#pragma unroll
        for (int k = 0; k < 16; k++) {
            float4 a = *(const float4*)&As[k * LDT + ty * 4];
            float4 w = *(const float4*)&Ws[k * LDT + tx * 4];
            acc[0][0] += a.x * w.x; acc[0][1] += a.x * w.y; acc[0][2] += a.x * w.z; acc[0][3] += a.x * w.w;
            acc[1][0] += a.y * w.x; acc[1][1] += a.y * w.y; acc[1][2] += a.y * w.z; acc[1][3] += a.y * w.w;
            acc[2][0] += a.z * w.x; acc[2][1] += a.z * w.y; acc[2][2] += a.z * w.z; acc[2][3] += a.z * w.w;
            acc[3][0] += a.w * w.x; acc[3][1] += a.w * w.y; acc[3][2] += a.w * w.z; acc[3][3] += a.w * w.w;
            if constexpr (DUAL) {
                float4 b = *(const float4*)&Bs[k * LDT + ty * 4];
                float4 w2 = *(const float4*)&W2s[k * LDT + tx * 4];
                acc[0][0] += b.x * w2.x; acc[0][1] += b.x * w2.y; acc[0][2] += b.x * w2.z; acc[0][3] += b.x * w2.w;
                acc[1][0] += b.y * w2.x; acc[1][1] += b.y * w2.y; acc[1][2] += b.y * w2.z; acc[1][3] += b.y * w2.w;
                acc[2][0] += b.z * w2.x; acc[2][1] += b.z * w2.y; acc[2][2] += b.z * w2.z; acc[2][3] += b.z * w2.w;
                acc[3][0] += b.w * w2.x; acc[3][1] += b.w * w2.y; acc[3][2] += b.w * w2.z; acc[3][3] += b.w * w2.w;
            }
        }
    }

    // epilogue
    const int nc = n0 + tx * 4;
    float4 b1v = *(const float4*)(bias1 + nc);
    float bb[4] = { b1v.x, b1v.y, b1v.z, b1v.w };
    if constexpr (DUAL) {
        float4 b2v = *(const float4*)(bias2 + nc);
        bb[0] += b2v.x; bb[1] += b2v.y; bb[2] += b2v.z; bb[3] += b2v.w;
    }
#pragma unroll
    for (int i = 0; i < 4; i++) {
        const int m = m0 + ty * 4 + i;
        float v[4];
#pragma unroll
        for (int j = 0; j < 4; j++) {
            float t = acc[i][j] + bb[j];
            if constexpr (ACT) t = gelu_f(t);
            v[j] = t;
        }
        if constexpr (RES) {
            float4 rv = *(const float4*)(A + (size_t)m * CH + nc);
            v[0] += rv.x; v[1] += rv.y; v[2] += rv.z; v[3] += rv.w;
        }
        *(float4*)(C + (size_t)m * NOUT + nc) = make_float4(v[0], v[1], v[2], v[3]);
    }
}

// ---------------------------------------------------------------------------
// zero fill (float4 grid-stride)
// ---------------------------------------------------------------------------
__global__ void zero_k(float* __restrict__ p, size_t n)
{
    size_t i = (size_t)blockIdx.x * blockDim.x + threadIdx.x;
    float4* p4 = (float4*)p;
    size_t n4 = n >> 2;
    for (size_t j = i; j < n4; j += (size_t)gridDim.x * blockDim.x)
        p4[j] = make_float4(0.f, 0.f, 0.f, 0.f);
}

// ---------------------------------------------------------------------------
// segment_sum: agg[dst[e]] += h[src[e]]   (one 64-lane wave per edge)
// ---------------------------------------------------------------------------
__global__ __launch_bounds__(256) void scatter_k(
    const float* __restrict__ h, const int* __restrict__ ei, float* __restrict__ agg)
{
    const int lane = threadIdx.x & 63;
    const int e = blockIdx.x * 4 + (threadIdx.x >> 6);
    const int src = ei[e];
    const int dst = ei[NEDGE + e];
    float4 v = ((const float4*)(h + (size_t)src * CH))[lane];
    float* d = agg + (size_t)dst * CH + lane * 4;
    atomicAdd(d + 0, v.x);
    atomicAdd(d + 1, v.y);
    atomicAdd(d + 2, v.z);
    atomicAdd(d + 3, v.w);
}

// ---------------------------------------------------------------------------
// Householder Q from 6 params (BD=4: 3 reflectors)
// ---------------------------------------------------------------------------
__device__ __forceinline__ void make_Q(const float* __restrict__ p, float Q[4][4])
{
#pragma unroll
    for (int i = 0; i < 4; i++)
#pragma unroll
        for (int j = 0; j < 4; j++) Q[i][j] = (i == j) ? 1.f : 0.f;
    int idx = 0;
#pragma unroll
    for (int j = 0; j < 3; j++) {
        float v[4] = {0.f, 0.f, 0.f, 0.f};
        v[j] = 1.f;
#pragma unroll
        for (int t = 0; t < 4; t++)
            if (t > j) v[t] = p[idx + t - (j + 1)];
        idx += 3 - j;
        float nrm = v[0]*v[0] + v[1]*v[1] + v[2]*v[2] + v[3]*v[3];
        float s = 2.f / nrm;
#pragma unroll
        for (int i = 0; i < 4; i++) {
            float qv = Q[i][0]*v[0] + Q[i][1]*v[1] + Q[i][2]*v[2] + Q[i][3]*v[3];
            float t0 = s * qv;
#pragma unroll
            for (int c = 0; c < 4; c++) Q[i][c] -= t0 * v[c];
        }
    }
}

// ---------------------------------------------------------------------------
// Bundle transform: out[n, b*4+c] = sum_d Qc[n,b] * in[n, b*4+d]
// TRANS=false: Q ; TRANS=true: Q^T.  Block = 4 nodes x 64 bundles.
// ---------------------------------------------------------------------------
template<bool TRANS>
__global__ __launch_bounds__(256) void bundle_k(
    const float* __restrict__ vin, const float* __restrict__ nr, float* __restrict__ out)
{
    __shared__ float pb[4 * NBP];
    const int n0 = blockIdx.x * 4;
    for (int i = threadIdx.x; i < 4 * NBP; i += 256)
        pb[i] = nr[(size_t)n0 * NBP + i];
    __syncthreads();
    const int ln = threadIdx.x >> 6;
    const int b  = threadIdx.x & 63;
    const int n  = n0 + ln;
    float Q[4][4];
    make_Q(&pb[ln * NBP + b * 6], Q);
    float4 xv = ((const float4*)(vin + (size_t)n * CH))[b];
    float in0 = xv.x, in1 = xv.y, in2 = xv.z, in3 = xv.w;
    float4 o;
    if constexpr (!TRANS) {
        o.x = Q[0][0]*in0 + Q[0][1]*in1 + Q[0][2]*in2 + Q[0][3]*in3;
        o.y = Q[1][0]*in0 + Q[1][1]*in1 + Q[1][2]*in2 + Q[1][3]*in3;
        o.z = Q[2][0]*in0 + Q[2][1]*in1 + Q[2][2]*in2 + Q[2][3]*in3;
        o.w = Q[3][0]*in0 + Q[3][1]*in1 + Q[3][2]*in2 + Q[3][3]*in3;
    } else {
        o.x = Q[0][0]*in0 + Q[1][0]*in1 + Q[2][0]*in2 + Q[3][0]*in3;
        o.y = Q[0][1]*in0 + Q[1][1]*in1 + Q[2][1]*in2 + Q[3][1]*in3;
        o.z = Q[0][2]*in0 + Q[1][2]*in1 + Q[2][2]*in2 + Q[3][2]*in3;
        o.w = Q[0][3]*in0 + Q[1][3]*in1 + Q[2][3]*in2 + Q[3][3]*in3;
    }
    ((float4*)(out + (size_t)n * CH))[b] = o;
}

// ---------------------------------------------------------------------------
// hs[g,v,d] += sum_n ev[g,n,v] * h[g,n,d]   (block: one graph x 128-node chunk)
// ---------------------------------------------------------------------------
__global__ __launch_bounds__(256) void spec_proj_k(
    const float* __restrict__ v, const float* __restrict__ eigvec, float* __restrict__ hs)
{
    const int g = blockIdx.x;
    const int nbase = g * NPG + blockIdx.y * 128;
    __shared__ float evs[16][32];
    float acc[32];
#pragma unroll
    for (int k = 0; k < 32; k++) acc[k] = 0.f;
    for (int nt = 0; nt < 128; nt += 16) {
        __syncthreads();
        for (int i = threadIdx.x; i < 512; i += 256) {
            int nn = i >> 5, kk = i & 31;
            evs[nn][kk] = eigvec[(size_t)(nbase + nt + nn) * KEIG + kk];
        }
        __syncthreads();
#pragma unroll 4
        for (int nn = 0; nn < 16; nn++) {
            float hv = v[(size_t)(nbase + nt + nn) * CH + threadIdx.x];
#pragma unroll
            for (int k = 0; k < 32; k++) acc[k] += evs[nn][k] * hv;
        }
    }
    float* o = hs + (size_t)g * KEIG * CH + threadIdx.x;
#pragma unroll
    for (int k = 0; k < 32; k++) atomicAdd(o + k * CH, acc[k]);
}

// ---------------------------------------------------------------------------
// hs[g,k,b*4+r] *= exp(-eigval[g,k] * taus[b])
// ---------------------------------------------------------------------------
__global__ void spec_scale_k(
    const float* __restrict__ eigval, const float* __restrict__ taus, float* __restrict__ hs)
{
    int i = blockIdx.x * 256 + threadIdx.x;        // < GG*KEIG*CH = 524288
    int d = i & 255;
    int gk = i >> 8;
    int g = gk >> 5, k = gk & 31;
    int b = d >> 2;
    hs[i] *= expf(-eigval[g * KEIG + k] * taus[b]);
}

// ---------------------------------------------------------------------------
// out[g,n,d] = sum_v ev[g,n,v] * hs[g,v,d]   (block: 64-node chunk; hs col in regs)
// ---------------------------------------------------------------------------
__global__ __launch_bounds__(256) void spec_reproj_k(
    const float* __restrict__ eigvec, const float* __restrict__ hs, float* __restrict__ out)
{
    const int g = blockIdx.x >> 4;
    const int nbase = g * NPG + (blockIdx.x & 15) * 64;
    float hsr[32];
    const float* hg = hs + (size_t)g * KEIG * CH + threadIdx.x;
#pragma unroll
    for (int k = 0; k < 32; k++) hsr[k] = hg[k * CH];
    __shared__ float evs[64][32];
    for (int i = threadIdx.x; i < 2048; i += 256) {
        int nn = i >> 5, kk = i & 31;
        evs[nn][kk] = eigvec[(size_t)(nbase + nn) * KEIG + kk];
    }
    __syncthreads();
    for (int nn = 0; nn < 64; nn++) {
        float a = 0.f;
#pragma unroll
        for (int k = 0; k < 32; k++) a += evs[nn][k] * hsr[k];
        out[(size_t)(nbase + nn) * CH + threadIdx.x] = a;
    }
}

// ---------------------------------------------------------------------------
extern "C" void kernel_launch(void* const* d_in, const int* in_sizes, int n_in,
                              void* d_out, int out_size, void* d_ws, size_t ws_size,
                              hipStream_t stream)
{
    const float* x      = (const float*)d_in[0];
    const float* eigvec = (const float*)d_in[1];
    const float* eigval = (const float*)d_in[2];
    const float* taus   = (const float*)d_in[3];
    const float* enc_w  = (const float*)d_in[4];
    const float* enc_b  = (const float*)d_in[5];
    const float* self_w = (const float*)d_in[6];
    const float* self_b = (const float*)d_in[7];
    const float* nb_w   = (const float*)d_in[8];
    const float* nb_b   = (const float*)d_in[9];
    const float* dec_w  = (const float*)d_in[10];
    const float* dec_b  = (const float*)d_in[11];
    const float* lin_w  = (const float*)d_in[12];
    const float* lin_b  = (const float*)d_in[13];
    const int*   ei     = (const int*)d_in[14];
    (void)in_sizes; (void)n_in; (void)out_size; (void)ws_size;

    float* ws = (float*)d_ws;
    const size_t SZ = (size_t)NN * CH;          // 16777216 floats
    float* b0  = ws;                            // h / h2
    float* b1  = ws + SZ;                       // agg (layers)
    float* b2  = ws + 2 * SZ;                   // h ping-pong
    float* nr  = ws + SZ;                       // node_rep [NN,384] (after layers; overlays b1 + half b2)
    float* vf1 = ws + 41943040;                 // [NN,256] bundle-transformed field / later h3
    float* hs  = ws + 58720256;                 // [64,32,256]
    float* h3  = vf1;
    // total ws use: 59,244,544 floats = 237 MB

    dim3 blk(256);

    // h = gelu(x @ enc_w + enc_b)
    gemm_k<256, false, true, false><<<dim3(4, 1024), blk, 0, stream>>>(
        x, nullptr, enc_w, enc_b, nullptr, nullptr, b0);

    float* cur = b0; float* nxt = b2;
    for (int k = 0; k < 2; k++) {
        zero_k<<<16384, blk, 0, stream>>>(b1, SZ);
        scatter_k<<<NEDGE / 4, blk, 0, stream>>>(cur, ei, b1);
        // h = gelu(h@self_w + self_b + agg@nb_w + nb_b) + h
        gemm_k<256, true, true, true><<<dim3(4, 1024), blk, 0, stream>>>(
            cur, b1, self_w + (size_t)k * 65536, self_b + k * 256,
            nb_w + (size_t)k * 65536, nb_b + k * 256, nxt);
        float* t = cur; cur = nxt; nxt = t;
    }
    // cur == b0 here

    // node_rep = h @ dec_w + dec_b
    gemm_k<384, false, false, false><<<dim3(6, 1024), blk, 0, stream>>>(
        cur, nullptr, dec_w, dec_b, nullptr, nullptr, nr);

    // vf1 = Q . x  (per bundle)
    bundle_k<false><<<NN / 4, blk, 0, stream>>>(x, nr, vf1);

    // spectral: hs = ev^T @ vf1 ; scale ; h2 = ev @ hs
    zero_k<<<512, blk, 0, stream>>>(hs, (size_t)GG * KEIG * CH);
    spec_proj_k<<<dim3(GG, 8), blk, 0, stream>>>(vf1, eigvec, hs);
    spec_scale_k<<<2048, blk, 0, stream>>>(eigval, taus, hs);
    spec_reproj_k<<<GG * 16, blk, 0, stream>>>(eigvec, hs, b0);

    // h3 = h2 @ lin_w + lin_b
    gemm_k<256, false, false, false><<<dim3(4, 1024), blk, 0, stream>>>(
        b0, nullptr, lin_w, lin_b, nullptr, nullptr, h3);

    // out = Q^T . h3
    bundle_k<true><<<NN / 4, blk, 0, stream>>>(h3, nr, (float*)d_out);
}

// Round 2
// 1445.227 us; speedup vs baseline: 3.2376x; 3.2376x over previous
//
#include <hip/hip_runtime.h>
#include <math.h>

// Problem constants
#define NN      65536
#define GG      64
#define NPG     1024
#define KEIG    32
#define NBUN    64
#define BDIM    4
#define CH      256        // IN_CH == GNN_DIM == NB*BD
#define NBP     384
#define NEDGE   524288

__device__ __forceinline__ float gelu_f(float x) {
    return 0.5f * x * (1.0f + erff(x * 0.70710678118654752440f));
}

// ---------------------------------------------------------------------------
// Tiled fp32 GEMM: C[m,n] = act( A@W1 + b1 (+ B@W2 + b2) ) (+ A residual)
// A,B: [NN, 256] row-major.  W: [256, NOUT] row-major.  C: [NN, NOUT].
// Block: 64x64 output tile, 256 threads, 4x4 micro-tile per thread, BK=16.
// ---------------------------------------------------------------------------
template<int NOUT, bool DUAL, bool ACT, bool RES>
__global__ __launch_bounds__(256) void gemm_k(
    const float* __restrict__ A, const float* __restrict__ B,
    const float* __restrict__ W1, const float* __restrict__ bias1,
    const float* __restrict__ W2, const float* __restrict__ bias2,
    float* __restrict__ C)
{
    constexpr int LDT = 68;   // row stride (floats); 272B rows keep float4 16B-aligned
    __shared__ float As[16 * LDT];
    __shared__ float Ws[16 * LDT];
    __shared__ float Bs[DUAL ? 16 * LDT : 1];
    __shared__ float W2s[DUAL ? 16 * LDT : 1];

    const int tid = threadIdx.x;
    const int tx = tid & 15;        // n micro-tile
    const int ty = tid >> 4;        // m micro-tile
    const int m0 = blockIdx.y * 64;
    const int n0 = blockIdx.x * 64;

    // loader coords
    const int lrow  = tid >> 2;          // 0..63  (A row within tile)
    const int lkq   = (tid & 3) * 4;     // 0,4,8,12 (k quad)
    const int lkrow = tid >> 4;          // 0..15  (W k-row)
    const int lnq   = (tid & 15) * 4;    // 0..60  (W n quad)

    const float* Ab  = A + (size_t)(m0 + lrow) * CH + lkq;
    const float* W1b = W1 + (size_t)lkrow * NOUT + n0 + lnq;
    const float* Bb  = DUAL ? (B + (size_t)(m0 + lrow) * CH + lkq) : nullptr;
    const float* W2b = DUAL ? (W2 + (size_t)lkrow * NOUT + n0 + lnq) : nullptr;

    float acc[4][4];
#pragma unroll
    for (int i = 0; i < 4; i++)
#pragma unroll
        for (int j = 0; j < 4; j++) acc[i][j] = 0.f;

    for (int k0 = 0; k0 < CH; k0 += 16) {
        float4 av = *(const float4*)(Ab + k0);
        float4 wv = *(const float4*)(W1b + (size_t)k0 * NOUT);
        float4 bv, w2v;
        if constexpr (DUAL) {
            bv  = *(const float4*)(Bb + k0);
            w2v = *(const float4*)(W2b + (size_t)k0 * NOUT);
        }
        __syncthreads();   // previous iteration's LDS reads done
        As[(lkq + 0) * LDT + lrow] = av.x;
        As[(lkq + 1) * LDT + lrow] = av.y;
        As[(lkq + 2) * LDT + lrow] = av.z;
        As[(lkq + 3) * LDT + lrow] = av.w;
        *(float4*)&Ws[lkrow * LDT + lnq] = wv;
        if constexpr (DUAL) {
            Bs[(lkq + 0) * LDT + lrow] = bv.x;
            Bs[(lkq + 1) * LDT + lrow] = bv.y;
            Bs[(lkq + 2) * LDT + lrow] = bv.z;
            Bs[(lkq + 3) * LDT + lrow] = bv.w;
            *(float4*)&W2s[lkrow * LDT + lnq] = w2v;
        }
        __syncthreads();
#pragma unroll
        for (int k = 0; k < 16; k++) {
            float4 a = *(const float4*)&As[k * LDT + ty * 4];
            float4 w = *(const float4*)&Ws[k * LDT + tx * 4];
            acc[0][0] += a.x * w.x; acc[0][1] += a.x * w.y; acc[0][2] += a.x * w.z; acc[0][3] += a.x * w.w;
            acc[1][0] += a.y * w.x; acc[1][1] += a.y * w.y; acc[1][2] += a.y * w.z; acc[1][3] += a.y * w.w;
            acc[2][0] += a.z * w.x; acc[2][1] += a.z * w.y; acc[2][2] += a.z * w.z; acc[2][3] += a.z * w.w;
            acc[3][0] += a.w * w.x; acc[3][1] += a.w * w.y; acc[3][2] += a.w * w.z; acc[3][3] += a.w * w.w;
            if constexpr (DUAL) {
                float4 b = *(const float4*)&Bs[k * LDT + ty * 4];
                float4 w2 = *(const float4*)&W2s[k * LDT + tx * 4];
                acc[0][0] += b.x * w2.x; acc[0][1] += b.x * w2.y; acc[0][2] += b.x * w2.z; acc[0][3] += b.x * w2.w;
                acc[1][0] += b.y * w2.x; acc[1][1] += b.y * w2.y; acc[1][2] += b.y * w2.z; acc[1][3] += b.y * w2.w;
                acc[2][0] += b.z * w2.x; acc[2][1] += b.z * w2.y; acc[2][2] += b.z * w2.z; acc[2][3] += b.z * w2.w;
                acc[3][0] += b.w * w2.x; acc[3][1] += b.w * w2.y; acc[3][2] += b.w * w2.z; acc[3][3] += b.w * w2.w;
            }
        }
    }

    // epilogue
    const int nc = n0 + tx * 4;
    float4 b1v = *(const float4*)(bias1 + nc);
    float bb[4] = { b1v.x, b1v.y, b1v.z, b1v.w };
    if constexpr (DUAL) {
        float4 b2v = *(const float4*)(bias2 + nc);
        bb[0] += b2v.x; bb[1] += b2v.y; bb[2] += b2v.z; bb[3] += b2v.w;
    }
#pragma unroll
    for (int i = 0; i < 4; i++) {
        const int m = m0 + ty * 4 + i;
        float v[4];
#pragma unroll
        for (int j = 0; j < 4; j++) {
            float t = acc[i][j] + bb[j];
            if constexpr (ACT) t = gelu_f(t);
            v[j] = t;
        }
        if constexpr (RES) {
            float4 rv = *(const float4*)(A + (size_t)m * CH + nc);
            v[0] += rv.x; v[1] += rv.y; v[2] += rv.z; v[3] += rv.w;
        }
        *(float4*)(C + (size_t)m * NOUT + nc) = make_float4(v[0], v[1], v[2], v[3]);
    }
}

// ---------------------------------------------------------------------------
// zero fill (float4 grid-stride)
// ---------------------------------------------------------------------------
__global__ void zero_k(float* __restrict__ p, size_t n)
{
    size_t i = (size_t)blockIdx.x * blockDim.x + threadIdx.x;
    float4* p4 = (float4*)p;
    size_t n4 = n >> 2;
    for (size_t j = i; j < n4; j += (size_t)gridDim.x * blockDim.x)
        p4[j] = make_float4(0.f, 0.f, 0.f, 0.f);
}

// ---------------------------------------------------------------------------
// CSR build: histogram of dst, exclusive scan, cursor fill
// ---------------------------------------------------------------------------
__global__ __launch_bounds__(256) void hist_k(const int* __restrict__ ei, int* __restrict__ deg)
{
    int e = blockIdx.x * 256 + threadIdx.x;
    if (e < NEDGE) atomicAdd(&deg[ei[NEDGE + e]], 1);
}

// single block, 1024 threads: exclusive scan of deg[0..NN) -> off, cursor
__global__ __launch_bounds__(1024) void scan_k(
    const int* __restrict__ deg, int* __restrict__ off, int* __restrict__ cursor)
{
    __shared__ int sh[1024];
    const int tid = threadIdx.x;
    const int base = tid * 64;
    int s = 0;
#pragma unroll 8
    for (int i = 0; i < 64; i++) s += deg[base + i];
    const int mysum = s;
    sh[tid] = s;
    __syncthreads();
    for (int ofs = 1; ofs < 1024; ofs <<= 1) {
        int v = (tid >= ofs) ? sh[tid - ofs] : 0;
        __syncthreads();
        sh[tid] += v;
        __syncthreads();
    }
    int running = sh[tid] - mysum;   // exclusive prefix of this thread's chunk
    for (int i = 0; i < 64; i++) {
        off[base + i] = running;
        cursor[base + i] = running;
        running += deg[base + i];
    }
    if (tid == 1023) off[NN] = running;
}

__global__ __launch_bounds__(256) void fill_k(
    const int* __restrict__ ei, int* __restrict__ cursor, int* __restrict__ csr)
{
    int e = blockIdx.x * 256 + threadIdx.x;
    if (e < NEDGE) {
        int d = ei[NEDGE + e];
        int pos = atomicAdd(&cursor[d], 1);
        csr[pos] = ei[e];   // src
    }
}

// ---------------------------------------------------------------------------
// Gather segment-sum: agg[n] = sum_{e: dst==n} h[src[e]]
// One 64-lane wave per node; lane owns a float4 column chunk of the 256-ch row.
// ---------------------------------------------------------------------------
__global__ __launch_bounds__(256) void gather_k(
    const float* __restrict__ h, const int* __restrict__ off,
    const int* __restrict__ csr, float* __restrict__ agg)
{
    const int lane = threadIdx.x & 63;
    const int n = blockIdx.x * 4 + (threadIdx.x >> 6);
    const int s0 = off[n];
    const int s1 = off[n + 1];
    float4 acc = make_float4(0.f, 0.f, 0.f, 0.f);
    int j = s0;
    for (; j + 1 < s1; j += 2) {
        int sa = csr[j];
        int sb = csr[j + 1];
        float4 va = ((const float4*)(h + (size_t)sa * CH))[lane];
        float4 vb = ((const float4*)(h + (size_t)sb * CH))[lane];
        acc.x += va.x + vb.x; acc.y += va.y + vb.y;
        acc.z += va.z + vb.z; acc.w += va.w + vb.w;
    }
    if (j < s1) {
        int sa = csr[j];
        float4 va = ((const float4*)(h + (size_t)sa * CH))[lane];
        acc.x += va.x; acc.y += va.y; acc.z += va.z; acc.w += va.w;
    }
    ((float4*)(agg + (size_t)n * CH))[lane] = acc;
}

// ---------------------------------------------------------------------------
// Householder Q from 6 params (BD=4: 3 reflectors)
// ---------------------------------------------------------------------------
__device__ __forceinline__ void make_Q(const float* __restrict__ p, float Q[4][4])
{
#pragma unroll
    for (int i = 0; i < 4; i++)
#pragma unroll
        for (int j = 0; j < 4; j++) Q[i][j] = (i == j) ? 1.f : 0.f;
    int idx = 0;
#pragma unroll
    for (int j = 0; j < 3; j++) {
        float v[4] = {0.f, 0.f, 0.f, 0.f};
        v[j] = 1.f;
#pragma unroll
        for (int t = 0; t < 4; t++)
            if (t > j) v[t] = p[idx + t - (j + 1)];
        idx += 3 - j;
        float nrm = v[0]*v[0] + v[1]*v[1] + v[2]*v[2] + v[3]*v[3];
        float s = 2.f / nrm;
#pragma unroll
        for (int i = 0; i < 4; i++) {
            float qv = Q[i][0]*v[0] + Q[i][1]*v[1] + Q[i][2]*v[2] + Q[i][3]*v[3];
            float t0 = s * qv;
#pragma unroll
            for (int c = 0; c < 4; c++) Q[i][c] -= t0 * v[c];
        }
    }
}

// ---------------------------------------------------------------------------
// Bundle transform: out[n, b*4+c] = sum_d Qc[n,b] * in[n, b*4+d]
// TRANS=false: Q ; TRANS=true: Q^T.  Block = 4 nodes x 64 bundles.
// ---------------------------------------------------------------------------
template<bool TRANS>
__global__ __launch_bounds__(256) void bundle_k(
    const float* __restrict__ vin, const float* __restrict__ nr, float* __restrict__ out)
{
    __shared__ float pb[4 * NBP];
    const int n0 = blockIdx.x * 4;
    for (int i = threadIdx.x; i < 4 * NBP; i += 256)
        pb[i] = nr[(size_t)n0 * NBP + i];
    __syncthreads();
    const int ln = threadIdx.x >> 6;
    const int b  = threadIdx.x & 63;
    const int n  = n0 + ln;
    float Q[4][4];
    make_Q(&pb[ln * NBP + b * 6], Q);
    float4 xv = ((const float4*)(vin + (size_t)n * CH))[b];
    float in0 = xv.x, in1 = xv.y, in2 = xv.z, in3 = xv.w;
    float4 o;
    if constexpr (!TRANS) {
        o.x = Q[0][0]*in0 + Q[0][1]*in1 + Q[0][2]*in2 + Q[0][3]*in3;
        o.y = Q[1][0]*in0 + Q[1][1]*in1 + Q[1][2]*in2 + Q[1][3]*in3;
        o.z = Q[2][0]*in0 + Q[2][1]*in1 + Q[2][2]*in2 + Q[2][3]*in3;
        o.w = Q[3][0]*in0 + Q[3][1]*in1 + Q[3][2]*in2 + Q[3][3]*in3;
    } else {
        o.x = Q[0][0]*in0 + Q[1][0]*in1 + Q[2][0]*in2 + Q[3][0]*in3;
        o.y = Q[0][1]*in0 + Q[1][1]*in1 + Q[2][1]*in2 + Q[3][1]*in3;
        o.z = Q[0][2]*in0 + Q[1][2]*in1 + Q[2][2]*in2 + Q[3][2]*in3;
        o.w = Q[0][3]*in0 + Q[1][3]*in1 + Q[2][3]*in2 + Q[3][3]*in3;
    }
    ((float4*)(out + (size_t)n * CH))[b] = o;
}

// ---------------------------------------------------------------------------
// hs[g,v,d] += sum_n ev[g,n,v] * h[g,n,d]   (block: one graph x 128-node chunk)
// ---------------------------------------------------------------------------
__global__ __launch_bounds__(256) void spec_proj_k(
    const float* __restrict__ v, const float* __restrict__ eigvec, float* __restrict__ hs)
{
    const int g = blockIdx.x;
    const int nbase = g * NPG + blockIdx.y * 128;
    __shared__ float evs[16][32];
    float acc[32];
#pragma unroll
    for (int k = 0; k < 32; k++) acc[k] = 0.f;
    for (int nt = 0; nt < 128; nt += 16) {
        __syncthreads();
        for (int i = threadIdx.x; i < 512; i += 256) {
            int nn = i >> 5, kk = i & 31;
            evs[nn][kk] = eigvec[(size_t)(nbase + nt + nn) * KEIG + kk];
        }
        __syncthreads();
#pragma unroll 4
        for (int nn = 0; nn < 16; nn++) {
            float hv = v[(size_t)(nbase + nt + nn) * CH + threadIdx.x];
#pragma unroll
            for (int k = 0; k < 32; k++) acc[k] += evs[nn][k] * hv;
        }
    }
    float* o = hs + (size_t)g * KEIG * CH + threadIdx.x;
#pragma unroll
    for (int k = 0; k < 32; k++) atomicAdd(o + k * CH, acc[k]);
}

// ---------------------------------------------------------------------------
// hs[g,k,b*4+r] *= exp(-eigval[g,k] * taus[b])
// ---------------------------------------------------------------------------
__global__ void spec_scale_k(
    const float* __restrict__ eigval, const float* __restrict__ taus, float* __restrict__ hs)
{
    int i = blockIdx.x * 256 + threadIdx.x;        // < GG*KEIG*CH = 524288
    int d = i & 255;
    int gk = i >> 8;
    int g = gk >> 5, k = gk & 31;
    int b = d >> 2;
    hs[i] *= expf(-eigval[g * KEIG + k] * taus[b]);
}

// ---------------------------------------------------------------------------
// out[g,n,d] = sum_v ev[g,n,v] * hs[g,v,d]   (block: 64-node chunk; hs col in regs)
// ---------------------------------------------------------------------------
__global__ __launch_bounds__(256) void spec_reproj_k(
    const float* __restrict__ eigvec, const float* __restrict__ hs, float* __restrict__ out)
{
    const int g = blockIdx.x >> 4;
    const int nbase = g * NPG + (blockIdx.x & 15) * 64;
    float hsr[32];
    const float* hg = hs + (size_t)g * KEIG * CH + threadIdx.x;
#pragma unroll
    for (int k = 0; k < 32; k++) hsr[k] = hg[k * CH];
    __shared__ float evs[64][32];
    for (int i = threadIdx.x; i < 2048; i += 256) {
        int nn = i >> 5, kk = i & 31;
        evs[nn][kk] = eigvec[(size_t)(nbase + nn) * KEIG + kk];
    }
    __syncthreads();
    for (int nn = 0; nn < 64; nn++) {
        float a = 0.f;
#pragma unroll
        for (int k = 0; k < 32; k++) a += evs[nn][k] * hsr[k];
        out[(size_t)(nbase + nn) * CH + threadIdx.x] = a;
    }
}

// ---------------------------------------------------------------------------
extern "C" void kernel_launch(void* const* d_in, const int* in_sizes, int n_in,
                              void* d_out, int out_size, void* d_ws, size_t ws_size,
                              hipStream_t stream)
{
    const float* x      = (const float*)d_in[0];
    const float* eigvec = (const float*)d_in[1];
    const float* eigval = (const float*)d_in[2];
    const float* taus   = (const float*)d_in[3];
    const float* enc_w  = (const float*)d_in[4];
    const float* enc_b  = (const float*)d_in[5];
    const float* self_w = (const float*)d_in[6];
    const float* self_b = (const float*)d_in[7];
    const float* nb_w   = (const float*)d_in[8];
    const float* nb_b   = (const float*)d_in[9];
    const float* dec_w  = (const float*)d_in[10];
    const float* dec_b  = (const float*)d_in[11];
    const float* lin_w  = (const float*)d_in[12];
    const float* lin_b  = (const float*)d_in[13];
    const int*   ei     = (const int*)d_in[14];
    (void)in_sizes; (void)n_in; (void)out_size; (void)ws_size;

    float* ws = (float*)d_ws;
    const size_t SZ = (size_t)NN * CH;          // 16777216 floats
    float* b0  = ws;                            // h / h2
    float* b1  = ws + SZ;                       // agg (layers)
    float* b2  = ws + 2 * SZ;                   // h ping-pong
    float* nr  = ws + SZ;                       // node_rep [NN,384] (after layers)
    float* vf1 = ws + 41943040;                 // [NN,256] bundle field / later h3
    float* hs  = ws + 58720256;                 // [64,32,256]
    float* h3  = vf1;
    // CSR region lives in [50331648, 58720256) — free during GNN layers,
    // dead before vf1/hs phase begins.
    int* csr_base = (int*)(ws + 50331648);
    int* off    = csr_base;                     // NN+1
    int* deg    = csr_base + 65792;             // NN
    int* cursor = csr_base + 131584;            // NN
    int* csr    = csr_base + 197376;            // NEDGE
    // high-water: unchanged from round 0 (237 MB)

    dim3 blk(256);

    // ---- CSR build (by dst) ----
    zero_k<<<256, blk, 0, stream>>>((float*)deg, (size_t)NN);
    hist_k<<<NEDGE / 256, blk, 0, stream>>>(ei, deg);
    scan_k<<<1, 1024, 0, stream>>>(deg, off, cursor);
    fill_k<<<NEDGE / 256, blk, 0, stream>>>(ei, cursor, csr);

    // h = gelu(x @ enc_w + enc_b)
    gemm_k<256, false, true, false><<<dim3(4, 1024), blk, 0, stream>>>(
        x, nullptr, enc_w, enc_b, nullptr, nullptr, b0);

    float* cur = b0; float* nxt = b2;
    for (int k = 0; k < 2; k++) {
        gather_k<<<NN / 4, blk, 0, stream>>>(cur, off, csr, b1);
        // h = gelu(h@self_w + self_b + agg@nb_w + nb_b) + h
        gemm_k<256, true, true, true><<<dim3(4, 1024), blk, 0, stream>>>(
            cur, b1, self_w + (size_t)k * 65536, self_b + k * 256,
            nb_w + (size_t)k * 65536, nb_b + k * 256, nxt);
        float* t = cur; cur = nxt; nxt = t;
    }
    // cur == b0 here

    // node_rep = h @ dec_w + dec_b
    gemm_k<384, false, false, false><<<dim3(6, 1024), blk, 0, stream>>>(
        cur, nullptr, dec_w, dec_b, nullptr, nullptr, nr);

    // vf1 = Q . x  (per bundle)
    bundle_k<false><<<NN / 4, blk, 0, stream>>>(x, nr, vf1);

    // spectral: hs = ev^T @ vf1 ; scale ; h2 = ev @ hs
    zero_k<<<512, blk, 0, stream>>>(hs, (size_t)GG * KEIG * CH);
    spec_proj_k<<<dim3(GG, 8), blk, 0, stream>>>(vf1, eigvec, hs);
    spec_scale_k<<<2048, blk, 0, stream>>>(eigval, taus, hs);
    spec_reproj_k<<<GG * 16, blk, 0, stream>>>(eigvec, hs, b0);

    // h3 = h2 @ lin_w + lin_b
    gemm_k<256, false, false, false><<<dim3(4, 1024), blk, 0, stream>>>(
        b0, nullptr, lin_w, lin_b, nullptr, nullptr, h3);

    // out = Q^T . h3
    bundle_k<true><<<NN / 4, blk, 0, stream>>>(h3, nr, (float*)d_out);
}

// Round 5
// 944.245 us; speedup vs baseline: 4.9553x; 1.5306x over previous
//
#include <hip/hip_runtime.h>
#include <math.h>

// Problem constants
#define NN      65536
#define GG      64
#define NPG     1024
#define KEIG    32
#define NBUN    64
#define BDIM    4
#define CH      256        // IN_CH == GNN_DIM == NB*BD
#define NBP     384
#define NEDGE   524288

using bf16x8 = __attribute__((ext_vector_type(8))) short;
using f32x4  = __attribute__((ext_vector_type(4))) float;

__device__ __forceinline__ float gelu_f(float x) {
    return 0.5f * x * (1.0f + erff(x * 0.70710678118654752440f));
}
__device__ __forceinline__ float bf2f(unsigned short u) {
    union { float f; unsigned int i; } w; w.i = ((unsigned int)u) << 16; return w.f;
}
__device__ __forceinline__ unsigned short f2bf(float f) {
    union { float f; unsigned int i; } w; w.f = f;
    unsigned int r = w.i + 0x7FFF + ((w.i >> 16) & 1);   // RNE
    return (unsigned short)(r >> 16);
}

#define GLL(g, l) __builtin_amdgcn_global_load_lds( \
    (const __attribute__((address_space(1))) void*)(g), \
    (__attribute__((address_space(3))) void*)(l), 16, 0, 0)

// ---------------------------------------------------------------------------
// bf16 MFMA GEMM, optionally split-precision (hi+lo bf16 ~ fp32):
//   C = post( A @ W ), A as bf16 hi(+lo), W transposed as Wt[NOUT,KTOT] hi(+lo).
// Block tile 128x128, 4 waves (2x2) of 64x64, BK=32, mfma_f32_16x16x32_bf16,
// global_load_lds(16B) with XOR-swizzled 16B chunks.
// SPLIT: 3 passes ah*bh + al*bh + ah*bl  (drops lo*lo, ~2^-18).
// DUAL: A = concat_k(A1, A2), KTOT=512.
// RESA: + (bf2f(A1h)+bf2f(A1l)) residual, read-only (requires NOUT==256).
// WF: write fp32 Cf.  WSP: write hi/lo bf16 pair.
// NOTE: outputs must be disjoint from ALL inputs (no in-place) — graph-replay
// safety; blocks read A rows that other blocks' epilogues would overwrite.
// ---------------------------------------------------------------------------
template<int NOUT, int KTOT, bool DUAL, bool SPLIT, bool ACT, bool RESA, bool WF, bool WSP>
__global__ __launch_bounds__(256) void mgemm_k(
    const unsigned short* __restrict__ A1h, const unsigned short* __restrict__ A1l,
    const unsigned short* __restrict__ A2h, const unsigned short* __restrict__ A2l,
    const unsigned short* __restrict__ Wth, const unsigned short* __restrict__ Wtl,
    const float* __restrict__ bias,
    float* __restrict__ Cf, unsigned short* __restrict__ Cbh,
    unsigned short* __restrict__ Cbl)
{
    __shared__ unsigned short Ahs[128 * 32];   // 8 KB each, 512 x 16B chunks
    __shared__ unsigned short Bhs[128 * 32];
    __shared__ unsigned short Als[SPLIT ? 128 * 32 : 1];
    __shared__ unsigned short Bls[SPLIT ? 128 * 32 : 1];

    const int tid  = threadIdx.x;
    const int lane = tid & 63;
    const int wave = tid >> 6;
    const int wm   = wave >> 1;        // wave m-tile (0..1)
    const int wn   = wave & 1;         // wave n-tile (0..1)
    const int m0   = blockIdx.y * 128;
    const int n0   = blockIdx.x * 128;

    // staging chunks: o = tid (rows 0..63) and o+256 (rows 64..127)
    // chunk o holds tile chunk (r = o>>2, c = ((o&3) - (o>>3)) & 3)
    const int o1 = tid,        r1 = o1 >> 2, c1 = ((o1 & 3) - (o1 >> 3)) & 3;
    const int o2 = tid + 256,  r2 = o2 >> 2, c2 = ((o2 & 3) - (o2 >> 3)) & 3;

    unsigned short* Ah1 = &Ahs[(wave * 64) * 8];          // wave-uniform bases
    unsigned short* Ah2 = &Ahs[(256 + wave * 64) * 8];
    unsigned short* Bh1 = &Bhs[(wave * 64) * 8];
    unsigned short* Bh2 = &Bhs[(256 + wave * 64) * 8];
    unsigned short* Al1 = SPLIT ? &Als[(wave * 64) * 8] : nullptr;
    unsigned short* Al2 = SPLIT ? &Als[(256 + wave * 64) * 8] : nullptr;
    unsigned short* Bl1 = SPLIT ? &Bls[(wave * 64) * 8] : nullptr;
    unsigned short* Bl2 = SPLIT ? &Bls[(256 + wave * 64) * 8] : nullptr;

    // fragment LDS element offsets: chunk(r,c) = r*4 + ((c + (r>>1)) & 3)
    int aoff[4], boff[4];
#pragma unroll
    for (int t = 0; t < 4; t++) {
        int ra = wm * 64 + t * 16 + (lane & 15);
        int rb = wn * 64 + t * 16 + (lane & 15);
        int cc = lane >> 4;
        aoff[t] = (ra * 4 + ((cc + (ra >> 1)) & 3)) * 8;
        boff[t] = (rb * 4 + ((cc + (rb >> 1)) & 3)) * 8;
    }

    f32x4 acc[4][4];
#pragma unroll
    for (int i = 0; i < 4; i++)
#pragma unroll
        for (int j = 0; j < 4; j++) acc[i][j] = 0.f;

    for (int k0 = 0; k0 < KTOT; k0 += 32) {
        const unsigned short* Ash = A1h;
        const unsigned short* Asl = A1l;
        int kk = k0;
        if (DUAL && k0 >= 256) { Ash = A2h; Asl = A2l; kk = k0 - 256; }
        __syncthreads();   // previous iteration's LDS reads done
        GLL(Ash + (size_t)(m0 + r1) * 256 + kk + c1 * 8, Ah1);
        GLL(Ash + (size_t)(m0 + r2) * 256 + kk + c2 * 8, Ah2);
        GLL(Wth + (size_t)(n0 + r1) * KTOT + k0 + c1 * 8, Bh1);
        GLL(Wth + (size_t)(n0 + r2) * KTOT + k0 + c2 * 8, Bh2);
        if constexpr (SPLIT) {
            GLL(Asl + (size_t)(m0 + r1) * 256 + kk + c1 * 8, Al1);
            GLL(Asl + (size_t)(m0 + r2) * 256 + kk + c2 * 8, Al2);
            GLL(Wtl + (size_t)(n0 + r1) * KTOT + k0 + c1 * 8, Bl1);
            GLL(Wtl + (size_t)(n0 + r2) * KTOT + k0 + c2 * 8, Bl2);
        }
        __syncthreads();
        bf16x8 ah[4], bh[4];
#pragma unroll
        for (int t = 0; t < 4; t++) ah[t] = *(const bf16x8*)&Ahs[aoff[t]];
#pragma unroll
        for (int t = 0; t < 4; t++) bh[t] = *(const bf16x8*)&Bhs[boff[t]];
#pragma unroll
        for (int mt = 0; mt < 4; mt++)
#pragma unroll
            for (int nt = 0; nt < 4; nt++)
                acc[mt][nt] = __builtin_amdgcn_mfma_f32_16x16x32_bf16(
                    ah[mt], bh[nt], acc[mt][nt], 0, 0, 0);
        if constexpr (SPLIT) {
            bf16x8 al[4], bl[4];
#pragma unroll
            for (int t = 0; t < 4; t++) al[t] = *(const bf16x8*)&Als[aoff[t]];
#pragma unroll
            for (int t = 0; t < 4; t++) bl[t] = *(const bf16x8*)&Bls[boff[t]];
#pragma unroll
            for (int mt = 0; mt < 4; mt++)
#pragma unroll
                for (int nt = 0; nt < 4; nt++)
                    acc[mt][nt] = __builtin_amdgcn_mfma_f32_16x16x32_bf16(
                        al[mt], bh[nt], acc[mt][nt], 0, 0, 0);
#pragma unroll
            for (int mt = 0; mt < 4; mt++)
#pragma unroll
                for (int nt = 0; nt < 4; nt++)
                    acc[mt][nt] = __builtin_amdgcn_mfma_f32_16x16x32_bf16(
                        ah[mt], bl[nt], acc[mt][nt], 0, 0, 0);
        }
    }

    // epilogue: C[m = quad*4+reg][n = lane&15] per 16x16 tile (m89 layout)
    const int rbase = (lane >> 4) * 4;
    const int ncol  = lane & 15;
#pragma unroll
    for (int mt = 0; mt < 4; mt++) {
#pragma unroll
        for (int nt = 0; nt < 4; nt++) {
            const int n = n0 + wn * 64 + nt * 16 + ncol;
            const float bs = bias[n];
#pragma unroll
            for (int i = 0; i < 4; i++) {
                const int m = m0 + wm * 64 + mt * 16 + rbase + i;
                const size_t idx = (size_t)m * NOUT + n;
                float v = acc[mt][nt][i] + bs;
                if (ACT) v = gelu_f(v);
                if (RESA) {   // residual from read-only A1 pair (NOUT==256)
                    const size_t ridx = (size_t)m * 256 + n;
                    v += bf2f(A1h[ridx]) + bf2f(A1l[ridx]);
                }
                if (WF) Cf[idx] = v;
                if (WSP) {
                    unsigned short hv = f2bf(v);
                    Cbh[idx] = hv;
                    Cbl[idx] = f2bf(v - bf2f(hv));
                }
            }
        }
    }
}

// ---------------------------------------------------------------------------
__global__ void zero_k(float* __restrict__ p, size_t n)
{
    size_t i = (size_t)blockIdx.x * blockDim.x + threadIdx.x;
    float4* p4 = (float4*)p;
    size_t n4 = n >> 2;
    for (size_t j = i; j < n4; j += (size_t)gridDim.x * blockDim.x)
        p4[j] = make_float4(0.f, 0.f, 0.f, 0.f);
}

// fp32 -> split bf16 (hi+lo), 4 elems/thread
__global__ __launch_bounds__(256) void cvtsp_k(
    const float* __restrict__ in, unsigned short* __restrict__ hi,
    unsigned short* __restrict__ lo)
{
    size_t i = (size_t)blockIdx.x * 256 + threadIdx.x;
    float4 v = ((const float4*)in)[i];
    ushort4 h, l;
    h.x = f2bf(v.x); l.x = f2bf(v.x - bf2f(h.x));
    h.y = f2bf(v.y); l.y = f2bf(v.y - bf2f(h.y));
    h.z = f2bf(v.z); l.z = f2bf(v.z - bf2f(h.z));
    h.w = f2bf(v.w); l.w = f2bf(v.w - bf2f(h.w));
    ((ushort4*)hi)[i] = h;
    ((ushort4*)lo)[i] = l;
}

// weight transpose+convert (split): Wh/Wl[n*ldw + koff + k] = split(W[k*N + n]); K=256
__global__ __launch_bounds__(256) void twtsp_k(
    const float* __restrict__ W, unsigned short* __restrict__ Wh,
    unsigned short* __restrict__ Wl, int N, int ldw, int koff)
{
    int i = blockIdx.x * 256 + threadIdx.x;   // over 256*N
    int k = i & 255, n = i >> 8;
    if (n < N) {
        float v = W[(size_t)k * N + n];
        unsigned short h = f2bf(v);
        Wh[(size_t)n * ldw + koff + k] = h;
        Wl[(size_t)n * ldw + koff + k] = f2bf(v - bf2f(h));
    }
}

// single bf16 weight transpose (lin)
__global__ __launch_bounds__(256) void twt_k(
    const float* __restrict__ W, unsigned short* __restrict__ Wt,
    int N, int ldw, int koff)
{
    int i = blockIdx.x * 256 + threadIdx.x;
    int k = i & 255, n = i >> 8;
    if (n < N) Wt[(size_t)n * ldw + koff + k] = f2bf(W[(size_t)k * N + n]);
}

__global__ void bcomb_k(const float* __restrict__ a, const float* __restrict__ b,
                        float* __restrict__ o)
{
    int i = blockIdx.x * 256 + threadIdx.x;
    if (i < 512) o[i] = a[i] + b[i];
}

// ---------------------------------------------------------------------------
// CSR build: histogram of dst, exclusive scan, cursor fill
// ---------------------------------------------------------------------------
__global__ __launch_bounds__(256) void hist_k(const int* __restrict__ ei, int* __restrict__ deg)
{
    int e = blockIdx.x * 256 + threadIdx.x;
    if (e < NEDGE) atomicAdd(&deg[ei[NEDGE + e]], 1);
}

__global__ __launch_bounds__(1024) void scan_k(
    const int* __restrict__ deg, int* __restrict__ off, int* __restrict__ cursor)
{
    __shared__ int sh[1024];
    const int tid = threadIdx.x;
    const int base = tid * 64;
    int s = 0;
#pragma unroll 8
    for (int i = 0; i < 64; i++) s += deg[base + i];
    const int mysum = s;
    sh[tid] = s;
    __syncthreads();
    for (int ofs = 1; ofs < 1024; ofs <<= 1) {
        int v = (tid >= ofs) ? sh[tid - ofs] : 0;
        __syncthreads();
        sh[tid] += v;
        __syncthreads();
    }
    int running = sh[tid] - mysum;
    for (int i = 0; i < 64; i++) {
        off[base + i] = running;
        cursor[base + i] = running;
        running += deg[base + i];
    }
    if (tid == 1023) off[NN] = running;
}

__global__ __launch_bounds__(256) void fill_k(
    const int* __restrict__ ei, int* __restrict__ cursor, int* __restrict__ csr)
{
    int e = blockIdx.x * 256 + threadIdx.x;
    if (e < NEDGE) {
        int d = ei[NEDGE + e];
        int pos = atomicAdd(&cursor[d], 1);
        csr[pos] = ei[e];   // src
    }
}

// ---------------------------------------------------------------------------
// Gather segment-sum over split bf16 h: fp32 accum, split bf16 out
// ---------------------------------------------------------------------------
__global__ __launch_bounds__(256) void gather_b_k(
    const unsigned short* __restrict__ hh, const unsigned short* __restrict__ hl,
    const int* __restrict__ off, const int* __restrict__ csr,
    unsigned short* __restrict__ ah, unsigned short* __restrict__ al)
{
    const int lane = threadIdx.x & 63;
    const int n = blockIdx.x * 4 + (threadIdx.x >> 6);
    const int s0 = off[n], s1 = off[n + 1];
    float a0 = 0.f, a1 = 0.f, a2 = 0.f, a3 = 0.f;
    for (int j = s0; j < s1; j++) {
        const size_t row = (size_t)csr[j] * CH;
        ushort4 vh = ((const ushort4*)(hh + row))[lane];
        ushort4 vl = ((const ushort4*)(hl + row))[lane];
        a0 += bf2f(vh.x) + bf2f(vl.x);
        a1 += bf2f(vh.y) + bf2f(vl.y);
        a2 += bf2f(vh.z) + bf2f(vl.z);
        a3 += bf2f(vh.w) + bf2f(vl.w);
    }
    ushort4 oh, ol;
    oh.x = f2bf(a0); ol.x = f2bf(a0 - bf2f(oh.x));
    oh.y = f2bf(a1); ol.y = f2bf(a1 - bf2f(oh.y));
    oh.z = f2bf(a2); ol.z = f2bf(a2 - bf2f(oh.z));
    oh.w = f2bf(a3); ol.w = f2bf(a3 - bf2f(oh.w));
    ((ushort4*)(ah + (size_t)n * CH))[lane] = oh;
    ((ushort4*)(al + (size_t)n * CH))[lane] = ol;
}

// ---------------------------------------------------------------------------
// Householder Q from 6 params (BD=4: 3 reflectors)
// ---------------------------------------------------------------------------
__device__ __forceinline__ void make_Q(const float* __restrict__ p, float Q[4][4])
{
#pragma unroll
    for (int i = 0; i < 4; i++)
#pragma unroll
        for (int j = 0; j < 4; j++) Q[i][j] = (i == j) ? 1.f : 0.f;
    int idx = 0;
#pragma unroll
    for (int j = 0; j < 3; j++) {
        float v[4] = {0.f, 0.f, 0.f, 0.f};
        v[j] = 1.f;
#pragma unroll
        for (int t = 0; t < 4; t++)
            if (t > j) v[t] = p[idx + t - (j + 1)];
        idx += 3 - j;
        float nrm = v[0]*v[0] + v[1]*v[1] + v[2]*v[2] + v[3]*v[3];
        float s = 2.f / nrm;
#pragma unroll
        for (int i = 0; i < 4; i++) {
            float qv = Q[i][0]*v[0] + Q[i][1]*v[1] + Q[i][2]*v[2] + Q[i][3]*v[3];
            float t0 = s * qv;
#pragma unroll
            for (int c = 0; c < 4; c++) Q[i][c] -= t0 * v[c];
        }
    }
}

template<bool TRANS>
__global__ __launch_bounds__(256) void bundle_k(
    const float* __restrict__ vin, const float* __restrict__ nr, float* __restrict__ out)
{
    __shared__ float pb[4 * NBP];
    const int n0 = blockIdx.x * 4;
    for (int i = threadIdx.x; i < 4 * NBP; i += 256)
        pb[i] = nr[(size_t)n0 * NBP + i];
    __syncthreads();
    const int ln = threadIdx.x >> 6;
    const int b  = threadIdx.x & 63;
    const int n  = n0 + ln;
    float Q[4][4];
    make_Q(&pb[ln * NBP + b * 6], Q);
    float4 xv = ((const float4*)(vin + (size_t)n * CH))[b];
    float in0 = xv.x, in1 = xv.y, in2 = xv.z, in3 = xv.w;
    float4 o;
    if constexpr (!TRANS) {
        o.x = Q[0][0]*in0 + Q[0][1]*in1 + Q[0][2]*in2 + Q[0][3]*in3;
        o.y = Q[1][0]*in0 + Q[1][1]*in1 + Q[1][2]*in2 + Q[1][3]*in3;
        o.z = Q[2][0]*in0 + Q[2][1]*in1 + Q[2][2]*in2 + Q[2][3]*in3;
        o.w = Q[3][0]*in0 + Q[3][1]*in1 + Q[3][2]*in2 + Q[3][3]*in3;
    } else {
        o.x = Q[0][0]*in0 + Q[1][0]*in1 + Q[2][0]*in2 + Q[3][0]*in3;
        o.y = Q[0][1]*in0 + Q[1][1]*in1 + Q[2][1]*in2 + Q[3][1]*in3;
        o.z = Q[0][2]*in0 + Q[1][2]*in1 + Q[2][2]*in2 + Q[3][2]*in3;
        o.w = Q[0][3]*in0 + Q[1][3]*in1 + Q[2][3]*in2 + Q[3][3]*in3;
    }
    ((float4*)(out + (size_t)n * CH))[b] = o;
}

// ---------------------------------------------------------------------------
// Spectral kernels
// ---------------------------------------------------------------------------
__global__ __launch_bounds__(256) void spec_proj_k(
    const float* __restrict__ v, const float* __restrict__ eigvec, float* __restrict__ hs)
{
    const int g = blockIdx.x;
    const int nbase = g * NPG + blockIdx.y * 128;
    __shared__ float evs[16][32];
    float acc[32];
#pragma unroll
    for (int k = 0; k < 32; k++) acc[k] = 0.f;
    for (int nt = 0; nt < 128; nt += 16) {
        __syncthreads();
        for (int i = threadIdx.x; i < 512; i += 256) {
            int nn = i >> 5, kk = i & 31;
            evs[nn][kk] = eigvec[(size_t)(nbase + nt + nn) * KEIG + kk];
        }
        __syncthreads();
#pragma unroll 4
        for (int nn = 0; nn < 16; nn++) {
            float hv = v[(size_t)(nbase + nt + nn) * CH + threadIdx.x];
#pragma unroll
            for (int k = 0; k < 32; k++) acc[k] += evs[nn][k] * hv;
        }
    }
    float* o = hs + (size_t)g * KEIG * CH + threadIdx.x;
#pragma unroll
    for (int k = 0; k < 32; k++) atomicAdd(o + k * CH, acc[k]);
}

__global__ void spec_scale_k(
    const float* __restrict__ eigval, const float* __restrict__ taus, float* __restrict__ hs)
{
    int i = blockIdx.x * 256 + threadIdx.x;
    int d = i & 255;
    int gk = i >> 8;
    int g = gk >> 5, k = gk & 31;
    int b = d >> 2;
    hs[i] *= expf(-eigval[g * KEIG + k] * taus[b]);
}

// out_b[g,n,d] (bf16) = sum_v ev[g,n,v] * hs[g,v,d]
__global__ __launch_bounds__(256) void spec_reproj_b_k(
    const float* __restrict__ eigvec, const float* __restrict__ hs,
    unsigned short* __restrict__ out_b)
{
    const int g = blockIdx.x >> 4;
    const int nbase = g * NPG + (blockIdx.x & 15) * 64;
    float hsr[32];
    const float* hg = hs + (size_t)g * KEIG * CH + threadIdx.x;
#pragma unroll
    for (int k = 0; k < 32; k++) hsr[k] = hg[k * CH];
    __shared__ float evs[64][32];
    for (int i = threadIdx.x; i < 2048; i += 256) {
        int nn = i >> 5, kk = i & 31;
        evs[nn][kk] = eigvec[(size_t)(nbase + nn) * KEIG + kk];
    }
    __syncthreads();
    for (int nn = 0; nn < 64; nn++) {
        float a = 0.f;
#pragma unroll
        for (int k = 0; k < 32; k++) a += evs[nn][k] * hsr[k];
        out_b[(size_t)(nbase + nn) * CH + threadIdx.x] = f2bf(a);
    }
}

// ---------------------------------------------------------------------------
extern "C" void kernel_launch(void* const* d_in, const int* in_sizes, int n_in,
                              void* d_out, int out_size, void* d_ws, size_t ws_size,
                              hipStream_t stream)
{
    const float* x      = (const float*)d_in[0];
    const float* eigvec = (const float*)d_in[1];
    const float* eigval = (const float*)d_in[2];
    const float* taus   = (const float*)d_in[3];
    const float* enc_w  = (const float*)d_in[4];
    const float* enc_b  = (const float*)d_in[5];
    const float* self_w = (const float*)d_in[6];
    const float* self_b = (const float*)d_in[7];
    const float* nb_w   = (const float*)d_in[8];
    const float* nb_b   = (const float*)d_in[9];
    const float* dec_w  = (const float*)d_in[10];
    const float* dec_b  = (const float*)d_in[11];
    const float* lin_w  = (const float*)d_in[12];
    const float* lin_b  = (const float*)d_in[13];
    const int*   ei     = (const int*)d_in[14];
    (void)in_sizes; (void)n_in; (void)out_size; (void)ws_size;

    float* ws = (float*)d_ws;
    // Each bf16 [NN,256] plane = 8388608 floats. Stream-ordered lifetimes:
    //  [0,        8388608)  x_hi   -> (layer1 out) h1_hi -> nrF part
    //  [8388608, 16777216)  x_lo   -> h1_lo              -> nrF part
    //  [16777216,25165824)  agg_hi                       -> nrF part
    //  [25165824,33554432)  agg_lo            -> vf1 part -> h3 part
    //  [33554432,41943040)  h0_hi             -> vf1 part -> h3 part
    //  [41943040,50331648)  h0_lo             -> hs, h2_b
    //  [50331648,51052545)  CSR ints (deg/off/cursor/csr) ; h2_b tail
    //  [51052548,51511812)  weights + lbias              (206 MB high-water)
    unsigned short* x_hi   = (unsigned short*)(ws);
    unsigned short* x_lo   = (unsigned short*)(ws + 8388608);
    unsigned short* h1_hi  = (unsigned short*)(ws);
    unsigned short* h1_lo  = (unsigned short*)(ws + 8388608);
    unsigned short* agg_hi = (unsigned short*)(ws + 16777216);
    unsigned short* agg_lo = (unsigned short*)(ws + 25165824);
    unsigned short* h0_hi  = (unsigned short*)(ws + 33554432);
    unsigned short* h0_lo  = (unsigned short*)(ws + 41943040);
    int* ibase  = (int*)(ws + 50331648);
    int* deg    = ibase;                 // NN
    int* off    = ibase + 65536;         // NN+1
    int* cursor = ibase + 131073;        // NN
    int* csr    = ibase + 196609;        // NEDGE  (ends 50331648+720897)
    float* wb = ws + 51052548;
    unsigned short* enc_h = (unsigned short*)(wb);
    unsigned short* enc_l = (unsigned short*)(wb + 32768);
    unsigned short* l1_h  = (unsigned short*)(wb + 65536);
    unsigned short* l1_l  = (unsigned short*)(wb + 131072);
    unsigned short* l2_h  = (unsigned short*)(wb + 196608);
    unsigned short* l2_l  = (unsigned short*)(wb + 262144);
    unsigned short* dec_h = (unsigned short*)(wb + 327680);
    unsigned short* dec_l = (unsigned short*)(wb + 376832);
    unsigned short* linwt = (unsigned short*)(wb + 425984);
    float* lbias = wb + 458752;          // [2,256]; ends wb+459264

    // phase-2 overlays (all source regions dead by first use):
    float* nrF  = ws;                    // [NN,384] fp32, dec out (x/h1+agg dead)
    float* vf1  = ws + 25165824;         // [NN,256] fp32 (agg_lo+h0_hi dead after dec)
    float* hs   = ws + 41943040;         // [64,32,256] fp32 (h0_lo dead)
    unsigned short* h2_b = (unsigned short*)(ws + 42467328); // (h0_lo tail+CSR dead)
    float* h3   = ws + 25165824;         // vf1 spot (vf1 dead after spec_proj)

    dim3 blk(256);

    // ---- prep ----
    cvtsp_k<<<16384, blk, 0, stream>>>(x, x_hi, x_lo);
    twtsp_k<<<256, blk, 0, stream>>>(enc_w, enc_h, enc_l, 256, 256, 0);
    twtsp_k<<<256, blk, 0, stream>>>(self_w,         l1_h, l1_l, 256, 512, 0);
    twtsp_k<<<256, blk, 0, stream>>>(nb_w,           l1_h, l1_l, 256, 512, 256);
    twtsp_k<<<256, blk, 0, stream>>>(self_w + 65536, l2_h, l2_l, 256, 512, 0);
    twtsp_k<<<256, blk, 0, stream>>>(nb_w + 65536,   l2_h, l2_l, 256, 512, 256);
    twtsp_k<<<384, blk, 0, stream>>>(dec_w, dec_h, dec_l, 384, 256, 0);
    twt_k<<<256, blk, 0, stream>>>(lin_w, linwt, 256, 256, 0);
    bcomb_k<<<2, blk, 0, stream>>>(self_b, nb_b, lbias);
    zero_k<<<64, blk, 0, stream>>>((float*)deg, (size_t)NN);
    hist_k<<<NEDGE / 256, blk, 0, stream>>>(ei, deg);
    scan_k<<<1, 1024, 0, stream>>>(deg, off, cursor);
    fill_k<<<NEDGE / 256, blk, 0, stream>>>(ei, cursor, csr);

    // ---- h0 = gelu(x @ enc_w + enc_b)  [split, ~fp32] ----
    mgemm_k<256, 256, false, true, true, false, false, true><<<dim3(2, 512), blk, 0, stream>>>(
        x_hi, x_lo, nullptr, nullptr, enc_h, enc_l, enc_b, nullptr, h0_hi, h0_lo);

    // ---- GNN layer 1: h1 = gelu([h0,agg]@W + b) + h0 ----
    gather_b_k<<<NN / 4, blk, 0, stream>>>(h0_hi, h0_lo, off, csr, agg_hi, agg_lo);
    mgemm_k<256, 512, true, true, true, true, false, true><<<dim3(2, 512), blk, 0, stream>>>(
        h0_hi, h0_lo, agg_hi, agg_lo, l1_h, l1_l, lbias, nullptr, h1_hi, h1_lo);

    // ---- GNN layer 2: h0 = gelu([h1,agg]@W + b) + h1 ----
    gather_b_k<<<NN / 4, blk, 0, stream>>>(h1_hi, h1_lo, off, csr, agg_hi, agg_lo);
    mgemm_k<256, 512, true, true, true, true, false, true><<<dim3(2, 512), blk, 0, stream>>>(
        h1_hi, h1_lo, agg_hi, agg_lo, l2_h, l2_l, lbias + 256, nullptr, h0_hi, h0_lo);

    // ---- node_rep = h0 @ dec_w + dec_b  [split] ----
    mgemm_k<384, 256, false, true, false, false, true, false><<<dim3(3, 512), blk, 0, stream>>>(
        h0_hi, h0_lo, nullptr, nullptr, dec_h, dec_l, dec_b, nrF, nullptr, nullptr);

    // ---- vf1 = Q . x ----
    bundle_k<false><<<NN / 4, blk, 0, stream>>>(x, nrF, vf1);

    // ---- spectral filter ----
    zero_k<<<512, blk, 0, stream>>>(hs, (size_t)GG * KEIG * CH);
    spec_proj_k<<<dim3(GG, 8), blk, 0, stream>>>(vf1, eigvec, hs);
    spec_scale_k<<<2048, blk, 0, stream>>>(eigval, taus, hs);
    spec_reproj_b_k<<<GG * 16, blk, 0, stream>>>(eigvec, hs, h2_b);

    // ---- h3 = h2 @ lin_w + lin_b  [single bf16] ----
    mgemm_k<256, 256, false, false, false, false, true, false><<<dim3(2, 512), blk, 0, stream>>>(
        h2_b, nullptr, nullptr, nullptr, linwt, nullptr, lin_b, h3, nullptr, nullptr);

    // ---- out = Q^T . h3 ----
    bundle_k<true><<<NN / 4, blk, 0, stream>>>(h3, nrF, (float*)d_out);
}

// Round 7
// 736.711 us; speedup vs baseline: 6.3512x; 1.2817x over previous
//
#include <hip/hip_runtime.h>
#include <math.h>

// Problem constants
#define NN      65536
#define GG      64
#define NPG     1024
#define KEIG    32
#define NBUN    64
#define BDIM    4
#define CH      256        // IN_CH == GNN_DIM == NB*BD
#define NBP     384
#define NEDGE   524288

using f16x8 = __attribute__((ext_vector_type(8))) _Float16;
using f16x4 = __attribute__((ext_vector_type(4))) _Float16;
using f32x4 = __attribute__((ext_vector_type(4))) float;

__device__ __forceinline__ float gelu_f(float x) {
    return 0.5f * x * (1.0f + erff(x * 0.70710678118654752440f));
}

#define GLL(g, l) __builtin_amdgcn_global_load_lds( \
    (const __attribute__((address_space(1))) void*)(g), \
    (__attribute__((address_space(3))) void*)(l), 16, 0, 0)

// ---------------------------------------------------------------------------
// fp16 MFMA GEMM: C = post( A[M,KTOT] @ W ), W transposed as Wt[NOUT,KTOT].
// Block tile 128x128, 4 waves (2x2) of 64x64, BK=32, mfma_f32_16x16x32_f16,
// global_load_lds(16B) with XOR-swizzled 16B chunks (conflict-free b128 reads).
// DUAL: A = concat_k(A1, A2), KTOT=512.
// RESA: + (float)A1[m,n] residual, read-only (requires NOUT==256).
// WF: write fp32 Cf.  W16: write fp16 C16.
// Outputs disjoint from ALL inputs (graph-replay safety).
// ---------------------------------------------------------------------------
template<int NOUT, int KTOT, bool DUAL, bool ACT, bool RESA, bool WF, bool W16>
__global__ __launch_bounds__(256) void mgemm_k(
    const _Float16* __restrict__ A1, const _Float16* __restrict__ A2,
    const _Float16* __restrict__ Wt, const float* __restrict__ bias,
    float* __restrict__ Cf, _Float16* __restrict__ C16)
{
    __shared__ _Float16 Alds[128 * 32];   // 8 KB, 512 x 16B chunks
    __shared__ _Float16 Blds[128 * 32];

    const int tid  = threadIdx.x;
    const int lane = tid & 63;
    const int wave = tid >> 6;
    const int wm   = wave >> 1;        // wave m-tile (0..1)
    const int wn   = wave & 1;         // wave n-tile (0..1)
    const int m0   = blockIdx.y * 128;
    const int n0   = blockIdx.x * 128;

    // staging chunks: o = tid (rows 0..63) and o+256 (rows 64..127)
    // chunk o holds tile chunk (r = o>>2, c = ((o&3) - (o>>3)) & 3)
    const int o1 = tid,        r1 = o1 >> 2, c1 = ((o1 & 3) - (o1 >> 3)) & 3;
    const int o2 = tid + 256,  r2 = o2 >> 2, c2 = ((o2 & 3) - (o2 >> 3)) & 3;

    _Float16* Al1 = &Alds[(wave * 64) * 8];          // wave-uniform bases
    _Float16* Al2 = &Alds[(256 + wave * 64) * 8];
    _Float16* Bl1 = &Blds[(wave * 64) * 8];
    _Float16* Bl2 = &Blds[(256 + wave * 64) * 8];

    // fragment LDS element offsets: chunk(r,c) = r*4 + ((c + (r>>1)) & 3)
    int aoff[4], boff[4];
#pragma unroll
    for (int t = 0; t < 4; t++) {
        int ra = wm * 64 + t * 16 + (lane & 15);
        int rb = wn * 64 + t * 16 + (lane & 15);
        int cc = lane >> 4;
        aoff[t] = (ra * 4 + ((cc + (ra >> 1)) & 3)) * 8;
        boff[t] = (rb * 4 + ((cc + (rb >> 1)) & 3)) * 8;
    }

    f32x4 acc[4][4];
#pragma unroll
    for (int i = 0; i < 4; i++)
#pragma unroll
        for (int j = 0; j < 4; j++) acc[i][j] = 0.f;

    for (int k0 = 0; k0 < KTOT; k0 += 32) {
        const _Float16* As = A1; int kk = k0;
        if (DUAL && k0 >= 256) { As = A2; kk = k0 - 256; }
        __syncthreads();   // previous iteration's LDS reads done
        GLL(As + (size_t)(m0 + r1) * 256 + kk + c1 * 8, Al1);
        GLL(As + (size_t)(m0 + r2) * 256 + kk + c2 * 8, Al2);
        GLL(Wt + (size_t)(n0 + r1) * KTOT + k0 + c1 * 8, Bl1);
        GLL(Wt + (size_t)(n0 + r2) * KTOT + k0 + c2 * 8, Bl2);
        __syncthreads();
        f16x8 av[4], bv[4];
#pragma unroll
        for (int t = 0; t < 4; t++) av[t] = *(const f16x8*)&Alds[aoff[t]];
#pragma unroll
        for (int t = 0; t < 4; t++) bv[t] = *(const f16x8*)&Blds[boff[t]];
#pragma unroll
        for (int mt = 0; mt < 4; mt++)
#pragma unroll
            for (int nt = 0; nt < 4; nt++)
                acc[mt][nt] = __builtin_amdgcn_mfma_f32_16x16x32_f16(
                    av[mt], bv[nt], acc[mt][nt], 0, 0, 0);
    }

    // epilogue: C[m = quad*4+reg][n = lane&15] per 16x16 tile (m89 layout)
    const int rbase = (lane >> 4) * 4;
    const int ncol  = lane & 15;
#pragma unroll
    for (int mt = 0; mt < 4; mt++) {
#pragma unroll
        for (int nt = 0; nt < 4; nt++) {
            const int n = n0 + wn * 64 + nt * 16 + ncol;
            const float bs = bias[n];
#pragma unroll
            for (int i = 0; i < 4; i++) {
                const int m = m0 + wm * 64 + mt * 16 + rbase + i;
                const size_t idx = (size_t)m * NOUT + n;
                float v = acc[mt][nt][i] + bs;
                if (ACT) v = gelu_f(v);
                if (RESA) v += (float)A1[(size_t)m * 256 + n];
                if (WF) Cf[idx] = v;
                if (W16) C16[idx] = (_Float16)v;
            }
        }
    }
}

// ---------------------------------------------------------------------------
__global__ void zero_k(float* __restrict__ p, size_t n)
{
    size_t i = (size_t)blockIdx.x * blockDim.x + threadIdx.x;
    float4* p4 = (float4*)p;
    size_t n4 = n >> 2;
    for (size_t j = i; j < n4; j += (size_t)gridDim.x * blockDim.x)
        p4[j] = make_float4(0.f, 0.f, 0.f, 0.f);
}

// fp32 -> fp16 convert (4 elems/thread)
__global__ __launch_bounds__(256) void cvt16_k(
    const float* __restrict__ in, _Float16* __restrict__ out)
{
    size_t i = (size_t)blockIdx.x * 256 + threadIdx.x;
    float4 v = ((const float4*)in)[i];
    f16x4 o = { (_Float16)v.x, (_Float16)v.y, (_Float16)v.z, (_Float16)v.w };
    ((f16x4*)out)[i] = o;
}

// weight transpose+convert: Wt[n*ldw + koff + k] = f16(W[k*N + n]); K=256
__global__ __launch_bounds__(256) void twt16_k(
    const float* __restrict__ W, _Float16* __restrict__ Wt,
    int N, int ldw, int koff)
{
    int i = blockIdx.x * 256 + threadIdx.x;   // over 256*N
    int k = i & 255, n = i >> 8;
    if (n < N) Wt[(size_t)n * ldw + koff + k] = (_Float16)W[(size_t)k * N + n];
}

__global__ void bcomb_k(const float* __restrict__ a, const float* __restrict__ b,
                        float* __restrict__ o)
{
    int i = blockIdx.x * 256 + threadIdx.x;
    if (i < 512) o[i] = a[i] + b[i];
}

// ---------------------------------------------------------------------------
// CSR build: histogram of dst, exclusive scan, cursor fill
// ---------------------------------------------------------------------------
__global__ __launch_bounds__(256) void hist_k(const int* __restrict__ ei, int* __restrict__ deg)
{
    int e = blockIdx.x * 256 + threadIdx.x;
    if (e < NEDGE) atomicAdd(&deg[ei[NEDGE + e]], 1);
}

__global__ __launch_bounds__(1024) void scan_k(
    const int* __restrict__ deg, int* __restrict__ off, int* __restrict__ cursor)
{
    __shared__ int sh[1024];
    const int tid = threadIdx.x;
    const int base = tid * 64;
    int s = 0;
#pragma unroll 8
    for (int i = 0; i < 64; i++) s += deg[base + i];
    const int mysum = s;
    sh[tid] = s;
    __syncthreads();
    for (int ofs = 1; ofs < 1024; ofs <<= 1) {
        int v = (tid >= ofs) ? sh[tid - ofs] : 0;
        __syncthreads();
        sh[tid] += v;
        __syncthreads();
    }
    int running = sh[tid] - mysum;
    for (int i = 0; i < 64; i++) {
        off[base + i] = running;
        cursor[base + i] = running;
        running += deg[base + i];
    }
    if (tid == 1023) off[NN] = running;
}

__global__ __launch_bounds__(256) void fill_k(
    const int* __restrict__ ei, int* __restrict__ cursor, int* __restrict__ csr)
{
    int e = blockIdx.x * 256 + threadIdx.x;
    if (e < NEDGE) {
        int d = ei[NEDGE + e];
        int pos = atomicAdd(&cursor[d], 1);
        csr[pos] = ei[e];   // src
    }
}

// ---------------------------------------------------------------------------
// Gather segment-sum over fp16 h: fp32 accum, fp16 out
// ---------------------------------------------------------------------------
__global__ __launch_bounds__(256) void gather16_k(
    const _Float16* __restrict__ h, const int* __restrict__ off,
    const int* __restrict__ csr, _Float16* __restrict__ agg)
{
    const int lane = threadIdx.x & 63;
    const int n = blockIdx.x * 4 + (threadIdx.x >> 6);
    const int s0 = off[n], s1 = off[n + 1];
    float a0 = 0.f, a1 = 0.f, a2 = 0.f, a3 = 0.f;
    int j = s0;
    for (; j + 1 < s1; j += 2) {
        f16x4 va = ((const f16x4*)(h + (size_t)csr[j] * CH))[lane];
        f16x4 vb = ((const f16x4*)(h + (size_t)csr[j + 1] * CH))[lane];
        a0 += (float)va[0] + (float)vb[0]; a1 += (float)va[1] + (float)vb[1];
        a2 += (float)va[2] + (float)vb[2]; a3 += (float)va[3] + (float)vb[3];
    }
    if (j < s1) {
        f16x4 va = ((const f16x4*)(h + (size_t)csr[j] * CH))[lane];
        a0 += (float)va[0]; a1 += (float)va[1]; a2 += (float)va[2]; a3 += (float)va[3];
    }
    f16x4 o = { (_Float16)a0, (_Float16)a1, (_Float16)a2, (_Float16)a3 };
    ((f16x4*)(agg + (size_t)n * CH))[lane] = o;
}

// ---------------------------------------------------------------------------
// Householder Q from 6 fp16 params (BD=4: 3 reflectors)
// ---------------------------------------------------------------------------
__device__ __forceinline__ void make_Q(const _Float16* __restrict__ p, float Q[4][4])
{
#pragma unroll
    for (int i = 0; i < 4; i++)
#pragma unroll
        for (int j = 0; j < 4; j++) Q[i][j] = (i == j) ? 1.f : 0.f;
    int idx = 0;
#pragma unroll
    for (int j = 0; j < 3; j++) {
        float v[4] = {0.f, 0.f, 0.f, 0.f};
        v[j] = 1.f;
#pragma unroll
        for (int t = 0; t < 4; t++)
            if (t > j) v[t] = (float)p[idx + t - (j + 1)];
        idx += 3 - j;
        float nrm = v[0]*v[0] + v[1]*v[1] + v[2]*v[2] + v[3]*v[3];
        float s = 2.f / nrm;
#pragma unroll
        for (int i = 0; i < 4; i++) {
            float qv = Q[i][0]*v[0] + Q[i][1]*v[1] + Q[i][2]*v[2] + Q[i][3]*v[3];
            float t0 = s * qv;
#pragma unroll
            for (int c = 0; c < 4; c++) Q[i][c] -= t0 * v[c];
        }
    }
}

// Bundle transform: block = 4 nodes x 64 bundles; node_rep is fp16
template<bool TRANS>
__global__ __launch_bounds__(256) void bundle_k(
    const float* __restrict__ vin, const _Float16* __restrict__ nr,
    float* __restrict__ out)
{
    __shared__ _Float16 pb[4 * NBP];
    const int n0 = blockIdx.x * 4;
    for (int i = threadIdx.x; i < 4 * NBP; i += 256)
        pb[i] = nr[(size_t)n0 * NBP + i];
    __syncthreads();
    const int ln = threadIdx.x >> 6;
    const int b  = threadIdx.x & 63;
    const int n  = n0 + ln;
    float Q[4][4];
    make_Q(&pb[ln * NBP + b * 6], Q);
    float4 xv = ((const float4*)(vin + (size_t)n * CH))[b];
    float in0 = xv.x, in1 = xv.y, in2 = xv.z, in3 = xv.w;
    float4 o;
    if constexpr (!TRANS) {
        o.x = Q[0][0]*in0 + Q[0][1]*in1 + Q[0][2]*in2 + Q[0][3]*in3;
        o.y = Q[1][0]*in0 + Q[1][1]*in1 + Q[1][2]*in2 + Q[1][3]*in3;
        o.z = Q[2][0]*in0 + Q[2][1]*in1 + Q[2][2]*in2 + Q[2][3]*in3;
        o.w = Q[3][0]*in0 + Q[3][1]*in1 + Q[3][2]*in2 + Q[3][3]*in3;
    } else {
        o.x = Q[0][0]*in0 + Q[1][0]*in1 + Q[2][0]*in2 + Q[3][0]*in3;
        o.y = Q[0][1]*in0 + Q[1][1]*in1 + Q[2][1]*in2 + Q[3][1]*in3;
        o.z = Q[0][2]*in0 + Q[1][2]*in1 + Q[2][2]*in2 + Q[3][2]*in3;
        o.w = Q[0][3]*in0 + Q[1][3]*in1 + Q[2][3]*in2 + Q[3][3]*in3;
    }
    ((float4*)(out + (size_t)n * CH))[b] = o;
}

// ---------------------------------------------------------------------------
// Spectral kernels
// ---------------------------------------------------------------------------
__global__ __launch_bounds__(256) void spec_proj_k(
    const float* __restrict__ v, const float* __restrict__ eigvec, float* __restrict__ hs)
{
    const int g = blockIdx.x;
    const int nbase = g * NPG + blockIdx.y * 128;
    __shared__ float evs[16][32];
    float acc[32];
#pragma unroll
    for (int k = 0; k < 32; k++) acc[k] = 0.f;
    for (int nt = 0; nt < 128; nt += 16) {
        __syncthreads();
        for (int i = threadIdx.x; i < 512; i += 256) {
            int nn = i >> 5, kk = i & 31;
            evs[nn][kk] = eigvec[(size_t)(nbase + nt + nn) * KEIG + kk];
        }
        __syncthreads();
#pragma unroll 4
        for (int nn = 0; nn < 16; nn++) {
            float hv = v[(size_t)(nbase + nt + nn) * CH + threadIdx.x];
#pragma unroll
            for (int k = 0; k < 32; k++) acc[k] += evs[nn][k] * hv;
        }
    }
    float* o = hs + (size_t)g * KEIG * CH + threadIdx.x;
#pragma unroll
    for (int k = 0; k < 32; k++) atomicAdd(o + k * CH, acc[k]);
}

// out16[g,n,d] = sum_v ev[g,n,v] * hs[g,v,d] * exp(-eigval[g,v]*taus[d>>2])
// (spec_scale fused into the hs load)
__global__ __launch_bounds__(256) void spec_reproj16_k(
    const float* __restrict__ eigvec, const float* __restrict__ hs,
    const float* __restrict__ eigval, const float* __restrict__ taus,
    _Float16* __restrict__ out16)
{
    const int g = blockIdx.x >> 4;
    const int nbase = g * NPG + (blockIdx.x & 15) * 64;
    const float tau = taus[threadIdx.x >> 2];
    float hsr[32];
    const float* hg = hs + (size_t)g * KEIG * CH + threadIdx.x;
#pragma unroll
    for (int k = 0; k < 32; k++)
        hsr[k] = hg[k * CH] * expf(-eigval[g * KEIG + k] * tau);
    __shared__ float evs[64][32];
    for (int i = threadIdx.x; i < 2048; i += 256) {
        int nn = i >> 5, kk = i & 31;
        evs[nn][kk] = eigvec[(size_t)(nbase + nn) * KEIG + kk];
    }
    __syncthreads();
    for (int nn = 0; nn < 64; nn++) {
        float a = 0.f;
#pragma unroll
        for (int k = 0; k < 32; k++) a += evs[nn][k] * hsr[k];
        out16[(size_t)(nbase + nn) * CH + threadIdx.x] = (_Float16)a;
    }
}

// ---------------------------------------------------------------------------
extern "C" void kernel_launch(void* const* d_in, const int* in_sizes, int n_in,
                              void* d_out, int out_size, void* d_ws, size_t ws_size,
                              hipStream_t stream)
{
    const float* x      = (const float*)d_in[0];
    const float* eigvec = (const float*)d_in[1];
    const float* eigval = (const float*)d_in[2];
    const float* taus   = (const float*)d_in[3];
    const float* enc_w  = (const float*)d_in[4];
    const float* enc_b  = (const float*)d_in[5];
    const float* self_w = (const float*)d_in[6];
    const float* self_b = (const float*)d_in[7];
    const float* nb_w   = (const float*)d_in[8];
    const float* nb_b   = (const float*)d_in[9];
    const float* dec_w  = (const float*)d_in[10];
    const float* dec_b  = (const float*)d_in[11];
    const float* lin_w  = (const float*)d_in[12];
    const float* lin_b  = (const float*)d_in[13];
    const int*   ei     = (const int*)d_in[14];
    (void)in_sizes; (void)n_in; (void)out_size; (void)ws_size;

    float* ws = (float*)d_ws;
    // fp16 [NN,256] plane = 16,777,216 halfs = 8,388,608 FLOAT-SLOTS (round-6
    // bug: was sized 4,194,304 -> agg stomped CSR -> wild gathers -> fault).
    // Stream-ordered lifetimes (float-slot offsets):
    //  [0,        8388608)  x16          -> vf1[0:half] / h3
    //  [8388608, 16777216)  h0           -> vf1[half:]  / h3
    //  [16777216,25165824)  h1           -> hs (@16.7M) ; free tail
    //  [25165824,33554432)  agg          -> nr16 part
    //  [33554432,34275329)  CSR ints     -> nr16 part
    //  [25165824,37748736)  nr16 [NN,384] fp16 (dec out; agg+CSR dead)
    //  [37748752,37995024)  weights + lbias
    //  [37995024,46383632)  h2 [NN,256] fp16
    // high-water: 46,383,632 fl = 185.5 MB
    _Float16* x16 = (_Float16*)(ws);
    _Float16* h0  = (_Float16*)(ws + 8388608);
    _Float16* h1  = (_Float16*)(ws + 16777216);
    _Float16* agg = (_Float16*)(ws + 25165824);
    int* ibase  = (int*)(ws + 33554432);
    int* deg    = ibase;                 // NN
    int* off    = ibase + 65536;         // NN+1
    int* cursor = ibase + 131073;        // NN
    int* csr    = ibase + 196609;        // NEDGE (ends slot 34275329)
    _Float16* nr16 = (_Float16*)(ws + 25165824);  // [NN,384] fp16
    float* wb = ws + 37748752;
    _Float16* enc16 = (_Float16*)(wb);            // [256,256]
    _Float16* l1w   = (_Float16*)(wb + 32768);    // [256,512]
    _Float16* l2w   = (_Float16*)(wb + 98304);    // [256,512]
    _Float16* dec16 = (_Float16*)(wb + 163840);   // [384,256]
    _Float16* lin16 = (_Float16*)(wb + 212992);   // [256,256]
    float* lbias = wb + 245760;                   // [2,256] (ends wb+246272)
    _Float16* h2 = (_Float16*)(ws + 37995024);    // [NN,256] fp16
    float* vf1 = ws;                              // [NN,256] fp32 (x16,h0 dead)
    float* hs  = ws + 16777216;                   // [64,32,256] fp32 (h1 dead)
    float* h3  = vf1;                             // vf1 dead after spec_proj

    dim3 blk(256);

    // ---- prep ----
    cvt16_k<<<16384, blk, 0, stream>>>(x, x16);
    twt16_k<<<256, blk, 0, stream>>>(enc_w, enc16, 256, 256, 0);
    twt16_k<<<256, blk, 0, stream>>>(self_w,         l1w, 256, 512, 0);
    twt16_k<<<256, blk, 0, stream>>>(nb_w,           l1w, 256, 512, 256);
    twt16_k<<<256, blk, 0, stream>>>(self_w + 65536, l2w, 256, 512, 0);
    twt16_k<<<256, blk, 0, stream>>>(nb_w + 65536,   l2w, 256, 512, 256);
    twt16_k<<<384, blk, 0, stream>>>(dec_w, dec16, 384, 256, 0);
    twt16_k<<<256, blk, 0, stream>>>(lin_w, lin16, 256, 256, 0);
    bcomb_k<<<2, blk, 0, stream>>>(self_b, nb_b, lbias);
    zero_k<<<64, blk, 0, stream>>>((float*)deg, (size_t)NN);
    hist_k<<<NEDGE / 256, blk, 0, stream>>>(ei, deg);
    scan_k<<<1, 1024, 0, stream>>>(deg, off, cursor);
    fill_k<<<NEDGE / 256, blk, 0, stream>>>(ei, cursor, csr);

    // ---- h0 = gelu(x @ enc_w + enc_b) ----
    mgemm_k<256, 256, false, true, false, false, true><<<dim3(2, 512), blk, 0, stream>>>(
        x16, nullptr, enc16, enc_b, nullptr, h0);

    // ---- GNN layer 1: h1 = gelu([h0,agg]@W + b) + h0 ----
    gather16_k<<<NN / 4, blk, 0, stream>>>(h0, off, csr, agg);
    mgemm_k<256, 512, true, true, true, false, true><<<dim3(2, 512), blk, 0, stream>>>(
        h0, agg, l1w, lbias, nullptr, h1);

    // ---- GNN layer 2: h0 = gelu([h1,agg]@W + b) + h1 ----
    gather16_k<<<NN / 4, blk, 0, stream>>>(h1, off, csr, agg);
    mgemm_k<256, 512, true, true, true, false, true><<<dim3(2, 512), blk, 0, stream>>>(
        h1, agg, l2w, lbias + 256, nullptr, h0);

    // ---- node_rep = h0 @ dec_w + dec_b  (fp16 out; agg+CSR dead) ----
    mgemm_k<384, 256, false, false, false, false, true><<<dim3(3, 512), blk, 0, stream>>>(
        h0, nullptr, dec16, dec_b, nullptr, nr16);

    // ---- vf1 = Q . x  (x16,h0 dead) ----
    bundle_k<false><<<NN / 4, blk, 0, stream>>>(x, nr16, vf1);

    // ---- spectral filter (scale fused into reproj) ----
    zero_k<<<512, blk, 0, stream>>>(hs, (size_t)GG * KEIG * CH);
    spec_proj_k<<<dim3(GG, 8), blk, 0, stream>>>(vf1, eigvec, hs);
    spec_reproj16_k<<<GG * 16, blk, 0, stream>>>(eigvec, hs, eigval, taus, h2);

    // ---- h3 = h2 @ lin_w + lin_b  (fp32 out; vf1 dead) ----
    mgemm_k<256, 256, false, false, false, true, false><<<dim3(2, 512), blk, 0, stream>>>(
        h2, nullptr, lin16, lin_b, h3, nullptr);

    // ---- out = Q^T . h3 ----
    bundle_k<true><<<NN / 4, blk, 0, stream>>>(h3, nr16, (float*)d_out);
}